// Round 1
// baseline (828.236 us; speedup 1.0000x reference)
//
#include <hip/hip_runtime.h>

// Problem constants (match reference)
#define B_ 2
#define S_ 2048
#define V_ 64
#define H_ 16
#define D_ 1024
static __device__ __constant__ float SCALE = 0.125f;  // 1/sqrt(V)

union F4 { float4 v; float f[4]; };

// ---------------------------------------------------------------------------
// Transpose [B, S*V, H] -> [B, H, S*V]   (per batch: [SV][16] -> [16][SV])
// ---------------------------------------------------------------------------
__global__ __launch_bounds__(256) void transpose_bsvh_to_bhsv(
    const float* __restrict__ in, float* __restrict__ out) {
  __shared__ float lds[16][260];  // [k][sv_local], pad to dodge conflicts
  const int t = threadIdx.x;
  const int a = blockIdx.y;
  const int base = blockIdx.x * 256;  // sv base (256 sv-positions per block)
  const float* src = in + (size_t)a * (S_ * V_ * H_) + (size_t)base * H_;
#pragma unroll
  for (int p = 0; p < 4; ++p) {
    float4 v = *reinterpret_cast<const float4*>(src + p * 1024 + t * 4);
    int e0 = p * 1024 + t * 4;
    int sv = e0 >> 4, k0 = e0 & 15;
    lds[k0 + 0][sv] = v.x;
    lds[k0 + 1][sv] = v.y;
    lds[k0 + 2][sv] = v.z;
    lds[k0 + 3][sv] = v.w;
  }
  __syncthreads();
  float* dst = out + (size_t)a * (H_ * S_ * V_) + base;
#pragma unroll
  for (int p = 0; p < 4; ++p) {
    int o0 = p * 1024 + t * 4;
    int k = o0 >> 8, pos = o0 & 255;
    float4 v = make_float4(lds[k][pos], lds[k][pos + 1], lds[k][pos + 2],
                           lds[k][pos + 3]);
    *reinterpret_cast<float4*>(dst + (size_t)k * (S_ * V_) + pos) = v;
  }
}

// ---------------------------------------------------------------------------
// Flash attention (fp32 vector). One block = 64 query rows of one (a,k) head.
// Qt/Kt/Vt: [B,H,S,V] contiguous. att written in ORIGINAL [B,S,V,H] layout.
// ---------------------------------------------------------------------------
__global__ __launch_bounds__(256) void attn_kernel(
    const float* __restrict__ Qt, const float* __restrict__ Kt,
    const float* __restrict__ Vt, float* __restrict__ att) {
  __shared__ float Qs[64][68];   // [row][feat]
  __shared__ float KsT[64][68];  // [feat][key]  (transposed K tile)
  __shared__ float Vs[64][64];   // [key][feat]
  __shared__ float Ps[64][68];   // [row][key]

  const int t = threadIdx.x;
  const int tx = t & 15, ty = t >> 4;
  int bid = blockIdx.x;
  const int k = bid & 15;          // head (innermost -> XCD L2 locality)
  const int qb = (bid >> 4) & 31;  // query block
  const int a = bid >> 9;          // batch

  const size_t headoff = ((size_t)a * H_ + k) * (size_t)(S_ * V_);
  const float* Qh = Qt + headoff + (size_t)qb * 64 * V_;
  const float* Kh = Kt + headoff;
  const float* Vh = Vt + headoff;

  // Load Q tile 64x64 (coalesced; 1 KiB per wave per pass)
#pragma unroll
  for (int p = 0; p < 4; ++p) {
    int c = (t >> 4) + p * 16;
    int q = t & 15;
    float4 v = *reinterpret_cast<const float4*>(Qh + c * V_ + q * 4);
    *reinterpret_cast<float4*>(&Qs[c][q * 4]) = v;
  }

  float O[4][4];
  float m_r[4], l_r[4];
#pragma unroll
  for (int i = 0; i < 4; ++i) {
    m_r[i] = -1e30f;
    l_r[i] = 0.f;
#pragma unroll
    for (int j = 0; j < 4; ++j) O[i][j] = 0.f;
  }

  for (int kt = 0; kt < S_ / 64; ++kt) {
    __syncthreads();  // previous iter's LDS reads done
    const float* Kb = Kh + (size_t)kt * 64 * V_;
    const float* Vb = Vh + (size_t)kt * 64 * V_;
#pragma unroll
    for (int p = 0; p < 4; ++p) {
      int c = (t >> 4) + p * 16;
      int q = t & 15;
      float4 v = *reinterpret_cast<const float4*>(Kb + c * V_ + q * 4);
      KsT[q * 4 + 0][c] = v.x;
      KsT[q * 4 + 1][c] = v.y;
      KsT[q * 4 + 2][c] = v.z;
      KsT[q * 4 + 3][c] = v.w;
      float4 w = *reinterpret_cast<const float4*>(Vb + c * V_ + q * 4);
      *reinterpret_cast<float4*>(&Vs[c][q * 4]) = w;
    }
    __syncthreads();

    // ---- QK^T: acc[i][j] = sum_b Qs[4ty+i][b] * KsT[b][4tx+j]
    float acc[4][4];
#pragma unroll
    for (int i = 0; i < 4; ++i)
#pragma unroll
      for (int j = 0; j < 4; ++j) acc[i][j] = 0.f;

#pragma unroll 4
    for (int b0 = 0; b0 < 64; b0 += 4) {
      F4 q4[4], k4[4];
#pragma unroll
      for (int i = 0; i < 4; ++i)
        q4[i].v = *reinterpret_cast<const float4*>(&Qs[4 * ty + i][b0]);
#pragma unroll
      for (int jb = 0; jb < 4; ++jb)
        k4[jb].v = *reinterpret_cast<const float4*>(&KsT[b0 + jb][4 * tx]);
#pragma unroll
      for (int i = 0; i < 4; ++i) {
#pragma unroll
        for (int jb = 0; jb < 4; ++jb) {
          float s = q4[i].f[jb];
          acc[i][0] += s * k4[jb].f[0];
          acc[i][1] += s * k4[jb].f[1];
          acc[i][2] += s * k4[jb].f[2];
          acc[i][3] += s * k4[jb].f[3];
        }
      }
    }

    // ---- online softmax (row stats in registers; identical across tx lanes)
#pragma unroll
    for (int i = 0; i < 4; ++i) {
#pragma unroll
      for (int j = 0; j < 4; ++j) acc[i][j] *= SCALE;
      float mx = fmaxf(fmaxf(acc[i][0], acc[i][1]), fmaxf(acc[i][2], acc[i][3]));
#pragma unroll
      for (int d = 1; d < 16; d <<= 1) mx = fmaxf(mx, __shfl_xor(mx, d, 64));
      float m_new = fmaxf(m_r[i], mx);
      float fac = __expf(m_r[i] - m_new);
      float rs = 0.f;
#pragma unroll
      for (int j = 0; j < 4; ++j) {
        float p = __expf(acc[i][j] - m_new);
        acc[i][j] = p;
        rs += p;
      }
#pragma unroll
      for (int d = 1; d < 16; d <<= 1) rs += __shfl_xor(rs, d, 64);
      l_r[i] = l_r[i] * fac + rs;
      m_r[i] = m_new;
#pragma unroll
      for (int j = 0; j < 4; ++j) O[i][j] *= fac;
      *reinterpret_cast<float4*>(&Ps[4 * ty + i][4 * tx]) =
          make_float4(acc[i][0], acc[i][1], acc[i][2], acc[i][3]);
    }
    __syncthreads();  // Ps visible

    // ---- PV: O[i][j] += sum_jj Ps[4ty+i][jj] * Vs[jj][4tx+j]
#pragma unroll 4
    for (int j0 = 0; j0 < 64; j0 += 4) {
      F4 p4[4], v4[4];
#pragma unroll
      for (int i = 0; i < 4; ++i)
        p4[i].v = *reinterpret_cast<const float4*>(&Ps[4 * ty + i][j0]);
#pragma unroll
      for (int jj = 0; jj < 4; ++jj)
        v4[jj].v = *reinterpret_cast<const float4*>(&Vs[j0 + jj][4 * tx]);
#pragma unroll
      for (int i = 0; i < 4; ++i) {
#pragma unroll
        for (int jj = 0; jj < 4; ++jj) {
          float s = p4[i].f[jj];
          O[i][0] += s * v4[jj].f[0];
          O[i][1] += s * v4[jj].f[1];
          O[i][2] += s * v4[jj].f[2];
          O[i][3] += s * v4[jj].f[3];
        }
      }
    }
  }

  // Epilogue: att[a, qb*64+r, v, k] = O / l   (original layout, scattered 4B)
#pragma unroll
  for (int i = 0; i < 4; ++i) {
    float inv = 1.f / l_r[i];
    int row = qb * 64 + 4 * ty + i;
    size_t base = (((size_t)a * S_ + row) * V_ + 4 * tx) * H_ + k;
#pragma unroll
    for (int j = 0; j < 4; ++j) att[base + (size_t)j * H_] = O[i][j] * inv;
  }
}

// ---------------------------------------------------------------------------
// Output projection: C[m][n] = sum_d A[m][d] * W[n][d] + bias[n]
// A = att [B*S, D] (contiguous in original layout), W = ov_w [D, D] row-major
// ---------------------------------------------------------------------------
__global__ __launch_bounds__(256) void proj_kernel(
    const float* __restrict__ A, const float* __restrict__ W,
    const float* __restrict__ bias, float* __restrict__ C) {
  __shared__ float As[64][36];   // [m-local][d-local], pad 36
  __shared__ float WsT[32][68];  // [d-local][n-local]
  const int t = threadIdx.x;
  const int tx = t & 15, ty = t >> 4;
  const int n0 = (blockIdx.x & 15) * 64;
  const int m0 = (blockIdx.x >> 4) * 64;

  float acc[4][4];
#pragma unroll
  for (int i = 0; i < 4; ++i)
#pragma unroll
    for (int j = 0; j < 4; ++j) acc[i][j] = 0.f;

  for (int d0 = 0; d0 < D_; d0 += 32) {
    __syncthreads();
    {
      int q = t & 7, c = t >> 3;  // c in 0..31
#pragma unroll
      for (int p = 0; p < 2; ++p) {
        int cc = c + p * 32;
        float4 v = *reinterpret_cast<const float4*>(
            A + (size_t)(m0 + cc) * D_ + d0 + q * 4);
        *reinterpret_cast<float4*>(&As[cc][q * 4]) = v;
        float4 w = *reinterpret_cast<const float4*>(
            W + (size_t)(n0 + cc) * D_ + d0 + q * 4);
        WsT[q * 4 + 0][cc] = w.x;
        WsT[q * 4 + 1][cc] = w.y;
        WsT[q * 4 + 2][cc] = w.z;
        WsT[q * 4 + 3][cc] = w.w;
      }
    }
    __syncthreads();
#pragma unroll
    for (int dq = 0; dq < 8; ++dq) {
      F4 a4[4], w4[4];
#pragma unroll
      for (int i = 0; i < 4; ++i)
        a4[i].v = *reinterpret_cast<const float4*>(&As[4 * ty + i][4 * dq]);
#pragma unroll
      for (int jj = 0; jj < 4; ++jj)
        w4[jj].v = *reinterpret_cast<const float4*>(&WsT[4 * dq + jj][4 * tx]);
#pragma unroll
      for (int i = 0; i < 4; ++i) {
#pragma unroll
        for (int jj = 0; jj < 4; ++jj) {
          float s = a4[i].f[jj];
          acc[i][0] += s * w4[jj].f[0];
          acc[i][1] += s * w4[jj].f[1];
          acc[i][2] += s * w4[jj].f[2];
          acc[i][3] += s * w4[jj].f[3];
        }
      }
    }
  }

  F4 bv;
  bv.v = *reinterpret_cast<const float4*>(bias + n0 + 4 * tx);
#pragma unroll
  for (int i = 0; i < 4; ++i) {
    float4 o = make_float4(acc[i][0] + bv.f[0], acc[i][1] + bv.f[1],
                           acc[i][2] + bv.f[2], acc[i][3] + bv.f[3]);
    *reinterpret_cast<float4*>(C + (size_t)(m0 + 4 * ty + i) * D_ + n0 +
                               4 * tx) = o;
  }
}

// ---------------------------------------------------------------------------
extern "C" void kernel_launch(void* const* d_in, const int* in_sizes, int n_in,
                              void* d_out, int out_size, void* d_ws,
                              size_t ws_size, hipStream_t stream) {
  const float* qv = (const float*)d_in[0];
  const float* kv = (const float*)d_in[1];
  const float* vv = (const float*)d_in[2];
  const float* ovw = (const float*)d_in[3];
  const float* ovb = (const float*)d_in[4];
  float* out = (float*)d_out;
  float* ws = (float*)d_ws;

  const size_t TSZ = (size_t)B_ * H_ * S_ * V_;  // 4,194,304 floats
  float* Qt = ws;
  float* Kt = ws + TSZ;
  float* Vt = ws + 2 * TSZ;
  float* att = ws + 3 * TSZ;  // total 64 MiB of workspace

  dim3 tgrid(S_ * V_ / 256, B_);
  transpose_bsvh_to_bhsv<<<tgrid, 256, 0, stream>>>(qv, Qt);
  transpose_bsvh_to_bhsv<<<tgrid, 256, 0, stream>>>(kv, Kt);
  transpose_bsvh_to_bhsv<<<tgrid, 256, 0, stream>>>(vv, Vt);

  // attention: grid = B * (S/64) * H, head innermost for XCD/L2 locality
  attn_kernel<<<B_ * (S_ / 64) * H_, 256, 0, stream>>>(Qt, Kt, Vt, att);

  // projection: grid = (M/64) * (N/64) = 64 * 16, n-tile innermost
  proj_kernel<<<((B_ * S_) / 64) * (D_ / 64), 256, 0, stream>>>(att, ovw, ovb,
                                                                out);
}

// Round 3
// 253.784 us; speedup vs baseline: 3.2635x; 3.2635x over previous
//
#include <hip/hip_runtime.h>

#define B_ 2
#define S_ 2048
#define V_ 64
#define H_ 16
#define D_ 1024

typedef __attribute__((ext_vector_type(8))) short bf16x8;
typedef __attribute__((ext_vector_type(4))) float f32x4;
typedef __attribute__((ext_vector_type(8))) unsigned short u16x8;
typedef __attribute__((ext_vector_type(4))) unsigned short u16x4;

// may_alias versions: ALL type-punned memory access goes through these.
// (Round-2 NaN root cause: ushort stores vs u64 loads of the same LDS array
// were TBAA-"non-aliasing" -> compiler reordered ds_read before ds_write.)
typedef unsigned long long __attribute__((may_alias)) ull_a;
typedef u16x8 __attribute__((may_alias)) u16x8_a;
typedef u16x4 __attribute__((may_alias)) u16x4_a;

union FR { bf16x8 v; unsigned long long u[2]; };

__device__ __forceinline__ unsigned short f2bf(float x) {
  union { float f; unsigned u; } c; c.f = x;
  unsigned r = c.u + 0x7fffu + ((c.u >> 16) & 1u);  // RNE
  return (unsigned short)(r >> 16);
}

__device__ __forceinline__ f32x4 MFMA(bf16x8 a, bf16x8 b, f32x4 c) {
  return __builtin_amdgcn_mfma_f32_16x16x32_bf16(a, b, c, 0, 0, 0);
}

// Read an 8-elem bf16 fragment (two stacked K=16 halves) from a row-major
// 64x64 ushort LDS tile whose 16B granules are XOR-swizzled by (row&7).
__device__ __forceinline__ void ldfrag(FR& fr, const unsigned short* arr,
                                       int row, int kbase) {
  int off = kbase & 7;
  int g0 = kbase >> 3;
  int g1 = (kbase + 16) >> 3;
  const unsigned short* rp = arr + row * 64;
  fr.u[0] = *(const ull_a*)(rp + ((g0 ^ (row & 7)) << 3) + off);
  fr.u[1] = *(const ull_a*)(rp + ((g1 ^ (row & 7)) << 3) + off);
}

// ---------------------------------------------------------------------------
// fp32 [B,S,V,H] -> bf16 [B,H,S,V], optional scale (folds 1/sqrt(V) into Q)
// ---------------------------------------------------------------------------
__global__ __launch_bounds__(256) void conv_qk(const float* __restrict__ in,
    unsigned short* __restrict__ outp, float scale) {
  __shared__ float lds[16][260];
  const int t = threadIdx.x;
  const int a = blockIdx.y;
  const int base = blockIdx.x * 256;
  const float* src = in + (size_t)a * (S_ * V_ * H_) + (size_t)base * H_;
#pragma unroll
  for (int p = 0; p < 4; ++p) {
    float4 v = *(const float4*)(src + p * 1024 + t * 4);
    int e0 = p * 1024 + t * 4;
    int sv = e0 >> 4, k0 = e0 & 15;
    lds[k0][sv] = v.x; lds[k0 + 1][sv] = v.y;
    lds[k0 + 2][sv] = v.z; lds[k0 + 3][sv] = v.w;
  }
  __syncthreads();
  unsigned short* dst = outp + (size_t)a * (H_ * S_ * V_) + base;
#pragma unroll
  for (int p = 0; p < 4; ++p) {
    int o0 = p * 1024 + t * 4;
    int hh = o0 >> 8, pos = o0 & 255;
    u16x4 o;
#pragma unroll
    for (int i = 0; i < 4; ++i) o[i] = f2bf(lds[hh][pos + i] * scale);
    *(u16x4_a*)(dst + (size_t)hh * (S_ * V_) + pos) = o;
  }
}

// ---------------------------------------------------------------------------
// fp32 vv [B,S,V,H] -> bf16 [B,H,V,S]  (feat-major so PV B-operand stages flat)
// ---------------------------------------------------------------------------
__global__ __launch_bounds__(256) void conv_v(const float* __restrict__ in,
    unsigned short* __restrict__ outp) {
  const int t = threadIdx.x;
  const int bid = blockIdx.x;
  const int sh = bid & 1, v = (bid >> 1) & 63, a = bid >> 7;
  const float* src = in + (size_t)a * (S_ * V_ * H_) + v * 16;
  unsigned short* dst = outp + (size_t)a * (H_ * V_ * S_) + (size_t)v * S_;
#pragma unroll 4
  for (int it = 0; it < 16; ++it) {
    int s = sh * 1024 + it * 64 + (t >> 2);
    int h0 = (t & 3) * 4;
    float4 x = *(const float4*)(src + (size_t)s * 1024 + h0);
    dst[(size_t)(h0 + 0) * (V_ * S_) + s] = f2bf(x.x);
    dst[(size_t)(h0 + 1) * (V_ * S_) + s] = f2bf(x.y);
    dst[(size_t)(h0 + 2) * (V_ * S_) + s] = f2bf(x.z);
    dst[(size_t)(h0 + 3) * (V_ * S_) + s] = f2bf(x.w);
  }
}

// ---------------------------------------------------------------------------
// fp32 ov_w [n][d] -> bf16 Wp[n][d'] with d' = h*64+v  (d = v*16+h)
// ---------------------------------------------------------------------------
__global__ __launch_bounds__(256) void conv_w(const float* __restrict__ Wf,
    unsigned short* __restrict__ Wp) {
  __shared__ float lds[64 * 17];
  const int t = threadIdx.x;
  const float* src = Wf + (size_t)blockIdx.x * D_;
  float4 x = *(const float4*)(src + t * 4);
#pragma unroll
  for (int i = 0; i < 4; ++i) {
    int d = t * 4 + i, v = d >> 4, hh = d & 15;
    lds[v * 17 + hh] = (&x.x)[i];
  }
  __syncthreads();
  u16x4 o;
#pragma unroll
  for (int i = 0; i < 4; ++i) {
    int dp = t * 4 + i, hh = dp >> 6, v = dp & 63;
    o[i] = f2bf(lds[v * 17 + hh]);
  }
  *(u16x4_a*)(Wp + (size_t)blockIdx.x * D_ + t * 4) = o;
}

// ---------------------------------------------------------------------------
// Flash attention, bf16 MFMA. Block = 64 q-rows of one (a,h); 4 waves.
// Qb,Kb: [B,H,S,V]; Vb: [B,H,V,S]; att out: bf16 [B,S,H,V] (= [token][d'])
// ---------------------------------------------------------------------------
__global__ __launch_bounds__(256) void attn_mfma(
    const unsigned short* __restrict__ Qb, const unsigned short* __restrict__ Kb,
    const unsigned short* __restrict__ Vb, unsigned short* __restrict__ att) {
  __shared__ unsigned short Ks[2][4096];
  __shared__ unsigned short Vs[2][4096];
  __shared__ unsigned short Ps[4096];

  const int t = threadIdx.x;
  const int l = t & 63, w = t >> 6;
  const int lo = l & 15, hx = l >> 4;

  const int bid = blockIdx.x;
  const int h = bid & 15, qb = (bid >> 4) & 31, a = bid >> 9;

  const size_t hoff = ((size_t)a * H_ + h) * (size_t)(S_ * V_);
  const unsigned short* Qh = Qb + hoff + (size_t)(qb * 64 + w * 16) * 64;
  const unsigned short* Kh = Kb + hoff;
  const unsigned short* Vh = Vb + hoff;  // V_*S_ == S_*V_

  // Q fragments (A-operand): lane l -> row lo, k = 4*hx + j (+16, +32ks)
  FR qf[2];
  {
    const unsigned short* qrow = Qh + lo * 64 + 4 * hx;
    qf[0].u[0] = *(const ull_a*)(qrow);
    qf[0].u[1] = *(const ull_a*)(qrow + 16);
    qf[1].u[0] = *(const ull_a*)(qrow + 32);
    qf[1].u[1] = *(const ull_a*)(qrow + 48);
  }

  f32x4 O[4];
  float m_[4], l_[4];
#pragma unroll
  for (int i = 0; i < 4; ++i) {
    m_[i] = -1e30f; l_[i] = 0.f;
    O[i][0] = O[i][1] = O[i][2] = O[i][3] = 0.f;
  }

  const int u0 = w * 128 + l;  // granule ids u0, u0+64 (512 granules = 8KB tile)
  u16x8 sK[2], sV[2];

  // prologue: stage tile 0
#pragma unroll
  for (int i = 0; i < 2; ++i) {
    int u = u0 + i * 64;
    sK[i] = *(const u16x8_a*)(Kh + u * 8);
    int f = u >> 3, kg = u & 7;
    sV[i] = *(const u16x8_a*)(Vh + (size_t)f * S_ + kg * 8);
  }
#pragma unroll
  for (int i = 0; i < 2; ++i) {
    int u = u0 + i * 64;
    int r = u >> 3, g = u & 7;
    *(u16x8_a*)(&Ks[0][r * 64 + ((g ^ (r & 7)) << 3)]) = sK[i];
    *(u16x8_a*)(&Vs[0][r * 64 + ((g ^ (r & 7)) << 3)]) = sV[i];
  }
  __syncthreads();

  int cur = 0;
  for (int kt = 0; kt < S_ / 64; ++kt) {
    const bool pre = (kt + 1 < S_ / 64);
    if (pre) {  // issue next-tile global loads early
      const unsigned short* Kt_ = Kh + (size_t)(kt + 1) * 64 * 64;
      const unsigned short* Vt_ = Vh + (size_t)(kt + 1) * 64;
#pragma unroll
      for (int i = 0; i < 2; ++i) {
        int u = u0 + i * 64;
        sK[i] = *(const u16x8_a*)(Kt_ + u * 8);
        int f = u >> 3, kg = u & 7;
        sV[i] = *(const u16x8_a*)(Vt_ + (size_t)f * S_ + kg * 8);
      }
    }

    // ---- QK^T: 8 MFMAs
    f32x4 acc[4];
#pragma unroll
    for (int cb = 0; cb < 4; ++cb)
      acc[cb][0] = acc[cb][1] = acc[cb][2] = acc[cb][3] = 0.f;
#pragma unroll
    for (int ks = 0; ks < 2; ++ks) {
      int kb = ks * 32 + 4 * hx;
#pragma unroll
      for (int cb = 0; cb < 4; ++cb) {
        FR kf; ldfrag(kf, Ks[cur], cb * 16 + lo, kb);
        acc[cb] = MFMA(qf[ks].v, kf.v, acc[cb]);
      }
    }

    // ---- online softmax (rows = 4*hx + r; reduce over 16 col lanes)
#pragma unroll
    for (int r = 0; r < 4; ++r) {
      float mx = fmaxf(fmaxf(acc[0][r], acc[1][r]), fmaxf(acc[2][r], acc[3][r]));
      mx = fmaxf(mx, __shfl_xor(mx, 1, 64));
      mx = fmaxf(mx, __shfl_xor(mx, 2, 64));
      mx = fmaxf(mx, __shfl_xor(mx, 4, 64));
      mx = fmaxf(mx, __shfl_xor(mx, 8, 64));
      float mn = fmaxf(m_[r], mx);
      float fac = __expf(m_[r] - mn);
      float rs = 0.f;
#pragma unroll
      for (int cb = 0; cb < 4; ++cb) {
        float p = __expf(acc[cb][r] - mn);
        acc[cb][r] = p; rs += p;
      }
      rs += __shfl_xor(rs, 1, 64);
      rs += __shfl_xor(rs, 2, 64);
      rs += __shfl_xor(rs, 4, 64);
      rs += __shfl_xor(rs, 8, 64);
      l_[r] = l_[r] * fac + rs;
      m_[r] = mn;
#pragma unroll
      for (int fb = 0; fb < 4; ++fb) O[fb][r] *= fac;
    }

    // ---- P -> LDS (bf16, swizzled)
#pragma unroll
    for (int r = 0; r < 4; ++r) {
      int q = w * 16 + hx * 4 + r;
      unsigned short* pp = &Ps[q * 64];
#pragma unroll
      for (int cb = 0; cb < 4; ++cb) {
        int k = cb * 16 + lo;
        pp[(((k >> 3) ^ (q & 7)) << 3) + (k & 7)] = f2bf(acc[cb][r]);
      }
    }
    // Order P stores before PV fragment reads (belt+suspenders w/ may_alias).
    __syncthreads();

    // ---- write staged next tile (late write)
    if (pre) {
      int nb = cur ^ 1;
#pragma unroll
      for (int i = 0; i < 2; ++i) {
        int u = u0 + i * 64;
        int r = u >> 3, g = u & 7;
        *(u16x8_a*)(&Ks[nb][r * 64 + ((g ^ (r & 7)) << 3)]) = sK[i];
        *(u16x8_a*)(&Vs[nb][r * 64 + ((g ^ (r & 7)) << 3)]) = sV[i];
      }
    }

    // ---- PV: 8 MFMAs
#pragma unroll
    for (int ks = 0; ks < 2; ++ks) {
      int kb = ks * 32 + 4 * hx;
      FR pf; ldfrag(pf, Ps, w * 16 + lo, kb);
#pragma unroll
      for (int fb = 0; fb < 4; ++fb) {
        FR vf; ldfrag(vf, Vs[cur], fb * 16 + lo, kb);
        O[fb] = MFMA(pf.v, vf.v, O[fb]);
      }
    }
    __syncthreads();
    cur ^= 1;
  }

  // ---- epilogue: att[a][s][h][v] bf16, coalesced 32B chunks
#pragma unroll
  for (int r = 0; r < 4; ++r) {
    float inv = 1.0f / l_[r];
    int s = qb * 64 + w * 16 + hx * 4 + r;
    unsigned short* op = att + (((size_t)a * S_ + s) * H_ + h) * V_;
#pragma unroll
    for (int fb = 0; fb < 4; ++fb)
      op[fb * 16 + lo] = f2bf(O[fb][r] * inv);
  }
}

// ---------------------------------------------------------------------------
// Projection: out[m][n] = sum_{d'} att'[m][d'] * Wp[n][d'] + bias[n]
// ---------------------------------------------------------------------------
__global__ __launch_bounds__(256) void proj_mfma(
    const unsigned short* __restrict__ A, const unsigned short* __restrict__ Wp,
    const float* __restrict__ bias, float* __restrict__ out) {
  __shared__ unsigned short As[2][4096];
  __shared__ unsigned short Ws[2][4096];
  const int t = threadIdx.x;
  const int l = t & 63, w = t >> 6, lo = l & 15, hx = l >> 4;
  const int n0 = (blockIdx.x & 15) * 64;
  const int m0 = (blockIdx.x >> 4) * 64;

  f32x4 acc[4];
#pragma unroll
  for (int cb = 0; cb < 4; ++cb)
    acc[cb][0] = acc[cb][1] = acc[cb][2] = acc[cb][3] = 0.f;

  const int u0 = w * 128 + l;
  u16x8 sA[2], sW[2];
#pragma unroll
  for (int i = 0; i < 2; ++i) {
    int u = u0 + i * 64;
    int r = u >> 3, g = u & 7;
    sA[i] = *(const u16x8_a*)(A + (size_t)(m0 + r) * D_ + g * 8);
    sW[i] = *(const u16x8_a*)(Wp + (size_t)(n0 + r) * D_ + g * 8);
  }
#pragma unroll
  for (int i = 0; i < 2; ++i) {
    int u = u0 + i * 64;
    int r = u >> 3, g = u & 7;
    *(u16x8_a*)(&As[0][r * 64 + ((g ^ (r & 7)) << 3)]) = sA[i];
    *(u16x8_a*)(&Ws[0][r * 64 + ((g ^ (r & 7)) << 3)]) = sW[i];
  }
  __syncthreads();

  int cur = 0;
  for (int dp = 0; dp < 16; ++dp) {
    const bool pre = (dp + 1 < 16);
    if (pre) {
#pragma unroll
      for (int i = 0; i < 2; ++i) {
        int u = u0 + i * 64;
        int r = u >> 3, g = u & 7;
        sA[i] = *(const u16x8_a*)(A + (size_t)(m0 + r) * D_ + (dp + 1) * 64 + g * 8);
        sW[i] = *(const u16x8_a*)(Wp + (size_t)(n0 + r) * D_ + (dp + 1) * 64 + g * 8);
      }
    }
#pragma unroll
    for (int ks = 0; ks < 2; ++ks) {
      int kb = ks * 32 + 4 * hx;
      FR af; ldfrag(af, As[cur], w * 16 + lo, kb);
#pragma unroll
      for (int cb = 0; cb < 4; ++cb) {
        FR wf; ldfrag(wf, Ws[cur], cb * 16 + lo, kb);
        acc[cb] = MFMA(af.v, wf.v, acc[cb]);
      }
    }
    if (pre) {
      int nb = cur ^ 1;
      __syncthreads();  // all waves done reading As[cur]? No: done STAGING? —
                        // ensures no wave still reads As[nb] from prev iter
                        // before we overwrite. (Writes below, then barrier.)
#pragma unroll
      for (int i = 0; i < 2; ++i) {
        int u = u0 + i * 64;
        int r = u >> 3, g = u & 7;
        *(u16x8_a*)(&As[nb][r * 64 + ((g ^ (r & 7)) << 3)]) = sA[i];
        *(u16x8_a*)(&Ws[nb][r * 64 + ((g ^ (r & 7)) << 3)]) = sW[i];
      }
      __syncthreads();
      cur = nb;
    }
  }

#pragma unroll
  for (int cb = 0; cb < 4; ++cb) {
    float bv = bias[n0 + cb * 16 + lo];
#pragma unroll
    for (int r = 0; r < 4; ++r)
      out[(size_t)(m0 + w * 16 + hx * 4 + r) * D_ + n0 + cb * 16 + lo] =
          acc[cb][r] + bv;
  }
}

// ---------------------------------------------------------------------------
extern "C" void kernel_launch(void* const* d_in, const int* in_sizes, int n_in,
                              void* d_out, int out_size, void* d_ws,
                              size_t ws_size, hipStream_t stream) {
  const float* qv = (const float*)d_in[0];
  const float* kv = (const float*)d_in[1];
  const float* vv = (const float*)d_in[2];
  const float* ovw = (const float*)d_in[3];
  const float* ovb = (const float*)d_in[4];
  float* out = (float*)d_out;

  const size_t NQK = (size_t)B_ * H_ * S_ * V_;  // 4,194,304
  unsigned short* Qb = (unsigned short*)d_ws;
  unsigned short* Kb = Qb + NQK;
  unsigned short* Vb = Kb + NQK;
  unsigned short* Wp = Vb + NQK;
  unsigned short* att = Wp + (size_t)D_ * D_;  // total ~35.7 MB

  conv_qk<<<dim3(512, 2), 256, 0, stream>>>(qv, Qb, 0.125f);
  conv_qk<<<dim3(512, 2), 256, 0, stream>>>(kv, Kb, 1.0f);
  conv_v<<<256, 256, 0, stream>>>(vv, Vb);
  conv_w<<<1024, 256, 0, stream>>>(ovw, Wp);

  attn_mfma<<<1024, 256, 0, stream>>>(Qb, Kb, Vb, att);
  proj_mfma<<<1024, 256, 0, stream>>>(att, Wp, ovb, out);
}

// Round 7
// 193.048 us; speedup vs baseline: 4.2903x; 1.3146x over previous
//
#include <hip/hip_runtime.h>

#define B_ 2
#define S_ 2048
#define V_ 64
#define H_ 16
#define D_ 1024

typedef __attribute__((ext_vector_type(8))) short bf16x8;
typedef __attribute__((ext_vector_type(4))) float f32x4;
typedef __attribute__((ext_vector_type(8))) unsigned short u16x8;
typedef __attribute__((ext_vector_type(4))) unsigned short u16x4;

// may_alias: ALL type-punned access (round-2 lesson: TBAA reordered LDS ops)
typedef unsigned long long __attribute__((may_alias)) ull_a;
typedef u16x8 __attribute__((may_alias)) u16x8_a;
typedef u16x4 __attribute__((may_alias)) u16x4_a;

union FR { bf16x8 v; unsigned long long u[2]; unsigned w[4]; };

template <int N> struct IC { static constexpr int v = N; };

__device__ __forceinline__ unsigned short f2bf(float x) {
  union { float f; unsigned u; } c; c.f = x;
  unsigned r = c.u + 0x7fffu + ((c.u >> 16) & 1u);  // RNE
  return (unsigned short)(r >> 16);
}

__device__ __forceinline__ unsigned cvtpk(float a, float b) {
  // dword = {lo: bf16(a), hi: bf16(b)}
  unsigned r;
  asm("v_cvt_pk_bf16_f32 %0, %1, %2" : "=v"(r) : "v"(a), "v"(b));
  return r;
}

__device__ __forceinline__ float ex2(float x) {
#if __has_builtin(__builtin_amdgcn_exp2f)
  return __builtin_amdgcn_exp2f(x);
#else
  return exp2f(x);
#endif
}

__device__ __forceinline__ f32x4 MFMA(bf16x8 a, bf16x8 b, f32x4 c) {
  return __builtin_amdgcn_mfma_f32_16x16x32_bf16(a, b, c, 0, 0, 0);
}

// ---------------------------------------------------------------------------
// fp32 [B,S,V,H] -> bf16 [B,H,S,V] for Q (scaled by 1/sqrt(V)*log2e) and K.
// ---------------------------------------------------------------------------
__global__ __launch_bounds__(256) void conv_qk2(
    const float* __restrict__ q, const float* __restrict__ k,
    unsigned short* __restrict__ Qb, unsigned short* __restrict__ Kb,
    float qscale) {
  __shared__ float lds[16][260];
  const int z = blockIdx.z;
  const float* in = z == 0 ? q : k;
  unsigned short* outp = z == 0 ? Qb : Kb;
  const float scale = z == 0 ? qscale : 1.0f;
  const int t = threadIdx.x;
  const int a = blockIdx.y;
  const int base = blockIdx.x * 256;
  const float* src = in + (size_t)a * (S_ * V_ * H_) + (size_t)base * H_;
#pragma unroll
  for (int p = 0; p < 4; ++p) {
    float4 vv4 = *(const float4*)(src + p * 1024 + t * 4);
    int e0 = p * 1024 + t * 4;
    int sv = e0 >> 4, k0 = e0 & 15;
    lds[k0][sv] = vv4.x; lds[k0 + 1][sv] = vv4.y;
    lds[k0 + 2][sv] = vv4.z; lds[k0 + 3][sv] = vv4.w;
  }
  __syncthreads();
  unsigned short* dst = outp + (size_t)a * (H_ * S_ * V_) + base;
#pragma unroll
  for (int p = 0; p < 4; ++p) {
    int o0 = p * 1024 + t * 4;
    int hh = o0 >> 8, pos = o0 & 255;
    u16x4 o;
#pragma unroll
    for (int i = 0; i < 4; ++i) o[i] = f2bf(lds[hh][pos + i] * scale);
    *(u16x4_a*)(dst + (size_t)hh * (S_ * V_) + pos) = o;
  }
}

// ---------------------------------------------------------------------------
// fp32 vv [B,S,V,H] -> bf16 [B,H,V,S] (feat-major; round-3-proven)
// ---------------------------------------------------------------------------
__global__ __launch_bounds__(256) void conv_v(const float* __restrict__ in,
    unsigned short* __restrict__ outp) {
  const int t = threadIdx.x;
  const int bid = blockIdx.x;
  const int sh = bid & 1, v = (bid >> 1) & 63, a = bid >> 7;
  const float* src = in + (size_t)a * (S_ * V_ * H_) + v * 16;
  unsigned short* dst = outp + (size_t)a * (H_ * V_ * S_) + (size_t)v * S_;
#pragma unroll 4
  for (int it = 0; it < 16; ++it) {
    int s = sh * 1024 + it * 64 + (t >> 2);
    int h0 = (t & 3) * 4;
    float4 x = *(const float4*)(src + (size_t)s * 1024 + h0);
    dst[(size_t)(h0 + 0) * (V_ * S_) + s] = f2bf(x.x);
    dst[(size_t)(h0 + 1) * (V_ * S_) + s] = f2bf(x.y);
    dst[(size_t)(h0 + 2) * (V_ * S_) + s] = f2bf(x.z);
    dst[(size_t)(h0 + 3) * (V_ * S_) + s] = f2bf(x.w);
  }
}

// ---------------------------------------------------------------------------
// fp32 ov_w [n][d] -> bf16 Wp[n][d'] with d' = h*64+v  (d = v*16+h)
// ---------------------------------------------------------------------------
__global__ __launch_bounds__(256) void conv_w(const float* __restrict__ Wf,
    unsigned short* __restrict__ Wp) {
  __shared__ float lds[64 * 17];
  const int t = threadIdx.x;
  const float* src = Wf + (size_t)blockIdx.x * D_;
  float4 x = *(const float4*)(src + t * 4);
#pragma unroll
  for (int i = 0; i < 4; ++i) {
    int d = t * 4 + i, v = d >> 4, hh = d & 15;
    lds[v * 17 + hh] = (&x.x)[i];
  }
  __syncthreads();
  u16x4 o;
#pragma unroll
  for (int i = 0; i < 4; ++i) {
    int dp = t * 4 + i, hh = dp >> 6, v = dp & 63;
    o[i] = f2bf(lds[v * 17 + hh]);
  }
  *(u16x4_a*)(Wp + (size_t)blockIdx.x * D_ + t * 4) = o;
}

// ---------------------------------------------------------------------------
// Flash attention, swapped-QK bf16 MFMA. Block = 128 q of one (a,h); 4 waves,
// 32 q per wave. K: [B,H,S,V]; V: [B,H,V,S] (feat-major).
// LDS tiles (both): row-major 64x64 ushort, 16B granule g stored at
// ((g ^ (row&7))<<3)  -> K rows = keys, V rows = feats (so LDS holds V^T).
// QK^T (swapped): S^T = mfma(A=K, B=Q); PV: O^T = mfma(A=V^T, B=P^T).
// att out: bf16 [B,S,H,V] = [token][d'].
// ---------------------------------------------------------------------------
__global__ __launch_bounds__(256, 2) void attn_mfma(
    const unsigned short* __restrict__ Qb, const unsigned short* __restrict__ Kb,
    const unsigned short* __restrict__ Vb, unsigned short* __restrict__ att) {
  __shared__ unsigned short Ks[2][4096];
  __shared__ unsigned short Vs[2][4096];

  const int t = threadIdx.x;
  const int l = t & 63, w = t >> 6;
  const int lo = l & 15, hx = l >> 4;

  const int bid = blockIdx.x;
  const int h = bid & 15, qb = (bid >> 4) & 15, a = bid >> 8;

  const size_t hoff = ((size_t)a * H_ + h) * (size_t)(S_ * V_);
  const unsigned short* Qh = Qb + hoff + (size_t)(qb * 128 + w * 32) * 64;
  const unsigned short* Kh = Kb + hoff;
  const unsigned short* Vh = Vb + hoff;  // [feat][key], key stride 1

  // Q fragments (B-operand): lane -> col q = qs*16+lo, k(feat) = 4hx+j (+16)
  FR qf[2][2];
#pragma unroll
  for (int qs = 0; qs < 2; ++qs) {
    const unsigned short* qrow = Qh + (qs * 16 + lo) * 64 + 4 * hx;
    qf[qs][0].u[0] = *(const ull_a*)(qrow);
    qf[qs][0].u[1] = *(const ull_a*)(qrow + 16);
    qf[qs][1].u[0] = *(const ull_a*)(qrow + 32);
    qf[qs][1].u[1] = *(const ull_a*)(qrow + 48);
  }

  // per-lane constant fragment-read offsets (ushort units): for a row
  // r = <blk>*16 + lo, the (ks,hf) granule is ((ks<<2)|(hf<<1)|(hx>>1))
  // un-swizzled with ^(lo&7); column-in-granule 4*(hx&1).
  int ok[2][2];
#pragma unroll
  for (int ks = 0; ks < 2; ++ks)
#pragma unroll
    for (int hf = 0; hf < 2; ++hf)
      ok[ks][hf] = lo * 64 + 4 * (hx & 1) +
                   ((((ks << 2) | (hf << 1) | (hx >> 1)) ^ (lo & 7)) << 3);
  const int u0 = w * 128 + l;  // staging granule ids: u0, u0+64
  const int wst = (u0 >> 3) * 64 + (((u0 & 7) ^ ((u0 >> 3) & 7)) << 3);

  f32x4 O[2][4];
  float m_[2], l_[2];
#pragma unroll
  for (int qs = 0; qs < 2; ++qs) {
    m_[qs] = -1e30f; l_[qs] = 0.f;
#pragma unroll
    for (int fb = 0; fb < 4; ++fb)
      O[qs][fb][0] = O[qs][fb][1] = O[qs][fb][2] = O[qs][fb][3] = 0.f;
  }

  u16x8 sK0, sK1, sV0, sV1;
  const int vf_ = u0 >> 3, vkg = u0 & 7;  // V granule: feat row, key-granule
  // prologue: stage tile 0 into buffer 0.
  // K second granule: u0+64 = ushort offset u0*8 + 512 (R5 bug: was 512*8).
  sK0 = *(const u16x8_a*)(Kh + u0 * 8);
  sK1 = *(const u16x8_a*)(Kh + u0 * 8 + 512);
  sV0 = *(const u16x8_a*)(Vh + (size_t)vf_ * S_ + vkg * 8);
  sV1 = *(const u16x8_a*)(Vh + (size_t)(vf_ + 8) * S_ + vkg * 8);
  *(u16x8_a*)(&Ks[0][wst]) = sK0;
  *(u16x8_a*)(&Ks[0][wst + 512]) = sK1;
  *(u16x8_a*)(&Vs[0][wst]) = sV0;
  *(u16x8_a*)(&Vs[0][wst + 512]) = sV1;
  __syncthreads();

  FR pb[2][2];

  auto tile = [&](int kt, auto cc) {
    constexpr int CUR = decltype(cc)::v;
    const bool pre = kt < S_ / 64 - 1;
    if (pre) {  // issue next-tile global loads early
      const unsigned short* Kt_ = Kh + (size_t)(kt + 1) * 4096;
      const unsigned short* Vt_ = Vh + (size_t)(kt + 1) * 64;
      sK0 = *(const u16x8_a*)(Kt_ + u0 * 8);
      sK1 = *(const u16x8_a*)(Kt_ + u0 * 8 + 512);
      sV0 = *(const u16x8_a*)(Vt_ + (size_t)vf_ * S_ + vkg * 8);
      sV1 = *(const u16x8_a*)(Vt_ + (size_t)(vf_ + 8) * S_ + vkg * 8);
    }

    // ---- QK^T (swapped): acc[qs][kb] = S^T[key = kb*16+4hx+r][q = qs*16+lo]
    f32x4 acc[2][4];
#pragma unroll
    for (int qs = 0; qs < 2; ++qs)
#pragma unroll
      for (int kb = 0; kb < 4; ++kb)
        acc[qs][kb][0] = acc[qs][kb][1] = acc[qs][kb][2] = acc[qs][kb][3] = 0.f;
#pragma unroll
    for (int ks = 0; ks < 2; ++ks) {
#pragma unroll
      for (int kb = 0; kb < 4; ++kb) {
        FR kf;
        kf.u[0] = *(const ull_a*)(&Ks[CUR][ok[ks][0] + kb * 1024]);
        kf.u[1] = *(const ull_a*)(&Ks[CUR][ok[ks][1] + kb * 1024]);
        acc[0][kb] = MFMA(kf.v, qf[0][ks].v, acc[0][kb]);
        acc[1][kb] = MFMA(kf.v, qf[1][ks].v, acc[1][kb]);
      }
    }

    // ---- softmax: per-lane query, keys in-register + 2 cross-hx shuffles
#pragma unroll
    for (int qs = 0; qs < 2; ++qs) {
      float x0 = fmaxf(fmaxf(acc[qs][0][0], acc[qs][0][1]),
                       fmaxf(acc[qs][0][2], acc[qs][0][3]));
      float x1 = fmaxf(fmaxf(acc[qs][1][0], acc[qs][1][1]),
                       fmaxf(acc[qs][1][2], acc[qs][1][3]));
      float x2 = fmaxf(fmaxf(acc[qs][2][0], acc[qs][2][1]),
                       fmaxf(acc[qs][2][2], acc[qs][2][3]));
      float x3 = fmaxf(fmaxf(acc[qs][3][0], acc[qs][3][1]),
                       fmaxf(acc[qs][3][2], acc[qs][3][3]));
      float mx = fmaxf(fmaxf(x0, x1), fmaxf(x2, x3));
      mx = fmaxf(mx, __shfl_xor(mx, 16, 64));
      mx = fmaxf(mx, __shfl_xor(mx, 32, 64));
      float mn = fmaxf(m_[qs], mx);
      float fac = ex2(m_[qs] - mn);
      float s0 = 0.f, s1 = 0.f, s2 = 0.f, s3 = 0.f;
#pragma unroll
      for (int kb = 0; kb < 4; ++kb) {
        float p0 = ex2(acc[qs][kb][0] - mn);
        float p1 = ex2(acc[qs][kb][1] - mn);
        float p2 = ex2(acc[qs][kb][2] - mn);
        float p3 = ex2(acc[qs][kb][3] - mn);
        acc[qs][kb][0] = p0; acc[qs][kb][1] = p1;
        acc[qs][kb][2] = p2; acc[qs][kb][3] = p3;
        s0 += p0; s1 += p1; s2 += p2; s3 += p3;
      }
      float rs = (s0 + s1) + (s2 + s3);
      rs += __shfl_xor(rs, 16, 64);
      rs += __shfl_xor(rs, 32, 64);
      l_[qs] = l_[qs] * fac + rs;
      m_[qs] = mn;
#pragma unroll
      for (int fb = 0; fb < 4; ++fb) {
        O[qs][fb][0] *= fac; O[qs][fb][1] *= fac;
        O[qs][fb][2] *= fac; O[qs][fb][3] *= fac;
      }
      // P^T -> bf16 B-fragments in-register: pb[qs][ks].u[hf] elem j
      //   = P^T[key = ks*32+hf*16+4hx+j][q] = acc[qs][2ks+hf][j]
#pragma unroll
      for (int ks = 0; ks < 2; ++ks) {
        pb[qs][ks].w[0] = cvtpk(acc[qs][2 * ks][0], acc[qs][2 * ks][1]);
        pb[qs][ks].w[1] = cvtpk(acc[qs][2 * ks][2], acc[qs][2 * ks][3]);
        pb[qs][ks].w[2] = cvtpk(acc[qs][2 * ks + 1][0], acc[qs][2 * ks + 1][1]);
        pb[qs][ks].w[3] = cvtpk(acc[qs][2 * ks + 1][2], acc[qs][2 * ks + 1][3]);
      }
    }

    // ---- write staged next tile (late write; vmcnt hidden under QK+softmax)
    if (pre) {
      *(u16x8_a*)(&Ks[CUR ^ 1][wst]) = sK0;
      *(u16x8_a*)(&Ks[CUR ^ 1][wst + 512]) = sK1;
      *(u16x8_a*)(&Vs[CUR ^ 1][wst]) = sV0;
      *(u16x8_a*)(&Vs[CUR ^ 1][wst + 512]) = sV1;
    }

    // ---- PV: O^T[feat][q] += mfma(A = V^T, B = P^T); V^T read = K pattern
#pragma unroll
    for (int ks = 0; ks < 2; ++ks) {
#pragma unroll
      for (int fb = 0; fb < 4; ++fb) {
        FR vf;
        vf.u[0] = *(const ull_a*)(&Vs[CUR][ok[ks][0] + fb * 1024]);
        vf.u[1] = *(const ull_a*)(&Vs[CUR][ok[ks][1] + fb * 1024]);
        O[0][fb] = MFMA(vf.v, pb[0][ks].v, O[0][fb]);
        O[1][fb] = MFMA(vf.v, pb[1][ks].v, O[1][fb]);
      }
    }
    __syncthreads();
  };

  for (int kt2 = 0; kt2 < S_ / 128; ++kt2) {
    tile(2 * kt2, IC<0>{});
    tile(2 * kt2 + 1, IC<1>{});
  }

  // ---- epilogue: att[a][s][h*64 + feat], feat = fb*16 + 4hx + r
#pragma unroll
  for (int qs = 0; qs < 2; ++qs) {
    float inv = 1.0f / l_[qs];
    int s = qb * 128 + w * 32 + qs * 16 + lo;
    unsigned short* op = att + (((size_t)a * S_ + s) * H_ + h) * V_ + 4 * hx;
#pragma unroll
    for (int fb = 0; fb < 4; ++fb) {
      union { u16x4 s4; unsigned w2[2]; } c;
      c.w2[0] = cvtpk(O[qs][fb][0] * inv, O[qs][fb][1] * inv);
      c.w2[1] = cvtpk(O[qs][fb][2] * inv, O[qs][fb][3] * inv);
      *(u16x4_a*)(op + fb * 16) = c.s4;
    }
  }
}

// ---------------------------------------------------------------------------
// Projection: out[m][n] = sum_{d'} att'[m][d'] * Wp[n][d'] + bias[n]
// Block = 128 rows x 64 cols, 4 waves (wave = 32 rows). K-step 64.
// ---------------------------------------------------------------------------
__global__ __launch_bounds__(256) void proj_mfma(
    const unsigned short* __restrict__ A, const unsigned short* __restrict__ Wp,
    const float* __restrict__ bias, float* __restrict__ out) {
  __shared__ unsigned short As[2][8192];  // 128 x 64
  __shared__ unsigned short Ws[2][4096];  // 64 x 64
  const int t = threadIdx.x;
  const int l = t & 63, w = t >> 6, lo = l & 15, hx = l >> 4;
  const int bid = blockIdx.x;
  const int n0 = (bid & 15) * 64;
  const int m0 = (bid >> 4) * 128;

  int ob[2][2];
#pragma unroll
  for (int ks = 0; ks < 2; ++ks)
#pragma unroll
    for (int hf = 0; hf < 2; ++hf)
      ob[ks][hf] = lo * 64 + 4 * (hx & 1) +
                   ((((ks << 2) | (hf << 1) | (hx >> 1)) ^ (lo & 7)) << 3);
  const int wbase = w * 2048;  // A-read extra offset: (w*32)*64

  f32x4 acc[2][4];
#pragma unroll
  for (int am = 0; am < 2; ++am)
#pragma unroll
    for (int cb = 0; cb < 4; ++cb)
      acc[am][cb][0] = acc[am][cb][1] = acc[am][cb][2] = acc[am][cb][3] = 0.f;

  u16x8 sA[4], sW[2];
  // prologue: stage dp=0 into buffer 0
#pragma unroll
  for (int p = 0; p < 4; ++p) {
    int u = t + p * 256;
    sA[p] = *(const u16x8_a*)(A + (size_t)(m0 + (u >> 3)) * D_ + (u & 7) * 8);
  }
#pragma unroll
  for (int p = 0; p < 2; ++p) {
    int u = t + p * 256;
    sW[p] = *(const u16x8_a*)(Wp + (size_t)(n0 + (u >> 3)) * D_ + (u & 7) * 8);
  }
#pragma unroll
  for (int p = 0; p < 4; ++p) {
    int u = t + p * 256;
    *(u16x8_a*)(&As[0][(u >> 3) * 64 + (((u & 7) ^ ((u >> 3) & 7)) << 3)]) = sA[p];
  }
#pragma unroll
  for (int p = 0; p < 2; ++p) {
    int u = t + p * 256;
    *(u16x8_a*)(&Ws[0][(u >> 3) * 64 + (((u & 7) ^ ((u >> 3) & 7)) << 3)]) = sW[p];
  }
  __syncthreads();

  auto tile = [&](int dp, auto cc) {
    constexpr int CUR = decltype(cc)::v;
    const bool pre = dp < D_ / 64 - 1;
    if (pre) {
#pragma unroll
      for (int p = 0; p < 4; ++p) {
        int u = t + p * 256;
        sA[p] = *(const u16x8_a*)(A + (size_t)(m0 + (u >> 3)) * D_ +
                                  (dp + 1) * 64 + (u & 7) * 8);
      }
#pragma unroll
      for (int p = 0; p < 2; ++p) {
        int u = t + p * 256;
        sW[p] = *(const u16x8_a*)(Wp + (size_t)(n0 + (u >> 3)) * D_ +
                                  (dp + 1) * 64 + (u & 7) * 8);
      }
    }
#pragma unroll
    for (int ks = 0; ks < 2; ++ks) {
      FR af0, af1;
      af0.u[0] = *(const ull_a*)(&As[CUR][wbase + ob[ks][0]]);
      af0.u[1] = *(const ull_a*)(&As[CUR][wbase + ob[ks][1]]);
      af1.u[0] = *(const ull_a*)(&As[CUR][wbase + ob[ks][0] + 1024]);
      af1.u[1] = *(const ull_a*)(&As[CUR][wbase + ob[ks][1] + 1024]);
#pragma unroll
      for (int cb = 0; cb < 4; ++cb) {
        FR wf;
        wf.u[0] = *(const ull_a*)(&Ws[CUR][ob[ks][0] + cb * 1024]);
        wf.u[1] = *(const ull_a*)(&Ws[CUR][ob[ks][1] + cb * 1024]);
        acc[0][cb] = MFMA(af0.v, wf.v, acc[0][cb]);
        acc[1][cb] = MFMA(af1.v, wf.v, acc[1][cb]);
      }
    }
    if (pre) {
#pragma unroll
      for (int p = 0; p < 4; ++p) {
        int u = t + p * 256;
        *(u16x8_a*)(&As[CUR ^ 1][(u >> 3) * 64 +
                                 (((u & 7) ^ ((u >> 3) & 7)) << 3)]) = sA[p];
      }
#pragma unroll
      for (int p = 0; p < 2; ++p) {
        int u = t + p * 256;
        *(u16x8_a*)(&Ws[CUR ^ 1][(u >> 3) * 64 +
                                 (((u & 7) ^ ((u >> 3) & 7)) << 3)]) = sW[p];
      }
    }
    __syncthreads();
  };

  for (int d2 = 0; d2 < D_ / 128; ++d2) {
    tile(2 * d2, IC<0>{});
    tile(2 * d2 + 1, IC<1>{});
  }

  float bv[4];
#pragma unroll
  for (int cb = 0; cb < 4; ++cb) bv[cb] = bias[n0 + cb * 16 + lo];
#pragma unroll
  for (int am = 0; am < 2; ++am) {
    int row = m0 + w * 32 + am * 16 + 4 * hx;
#pragma unroll
    for (int cb = 0; cb < 4; ++cb)
#pragma unroll
      for (int r = 0; r < 4; ++r)
        out[(size_t)(row + r) * D_ + n0 + cb * 16 + lo] = acc[am][cb][r] + bv[cb];
  }
}

// ---------------------------------------------------------------------------
extern "C" void kernel_launch(void* const* d_in, const int* in_sizes, int n_in,
                              void* d_out, int out_size, void* d_ws,
                              size_t ws_size, hipStream_t stream) {
  const float* qv = (const float*)d_in[0];
  const float* kv = (const float*)d_in[1];
  const float* vv = (const float*)d_in[2];
  const float* ovw = (const float*)d_in[3];
  const float* ovb = (const float*)d_in[4];
  float* out = (float*)d_out;

  const size_t NQK = (size_t)B_ * H_ * S_ * V_;  // 4,194,304
  unsigned short* Qb = (unsigned short*)d_ws;
  unsigned short* Kb = Qb + NQK;
  unsigned short* Vb = Kb + NQK;
  unsigned short* Wp = Vb + NQK;
  unsigned short* att = Wp + (size_t)D_ * D_;  // ~34 MB total

  // qscale = 1/sqrt(V) * log2(e): softmax computed in exp2 domain
  conv_qk2<<<dim3(512, 2, 2), 256, 0, stream>>>(qv, kv, Qb, Kb, 0.180336881f);
  conv_v<<<256, 256, 0, stream>>>(vv, Vb);
  conv_w<<<1024, 256, 0, stream>>>(ovw, Wp);

  attn_mfma<<<512, 256, 0, stream>>>(Qb, Kb, Vb, att);
  proj_mfma<<<512, 256, 0, stream>>>(att, Wp, ovb, out);
}